// Round 3
// baseline (3756.837 us; speedup 1.0000x reference)
//
#include <hip/hip_runtime.h>
#include <stdint.h>

#define DFEAT 300
#define XSTR 312          // Xt leading dim (u16): 16B-aligned rows, pads 300..311 zeroed

typedef unsigned short u16;
using short8 = __attribute__((ext_vector_type(8))) short;
using f32x4  = __attribute__((ext_vector_type(4))) float;

__device__ __forceinline__ float b2f(u16 u) {
    return __uint_as_float(((unsigned)u) << 16);
}
__device__ __forceinline__ u16 f2b(float f) {
    unsigned u = __float_as_uint(f);
    return (u16)((u + 0x7FFFu + ((u >> 16) & 1u)) >> 16);   // RNE
}
__device__ __forceinline__ float scrub(float v) {           // kill NaN/Inf (fast-math-proof)
    unsigned u = __float_as_uint(v);
    return (((u >> 23) & 0xFFu) == 0xFFu) ? 0.f : v;
}
__device__ __forceinline__ u16 sb16(u16 v) {
    return (((v >> 7) & 0xFFu) == 0xFFu) ? (u16)0 : v;
}

// ---------------- dtype sniffer: bf16 N(0,1) => ~100% sane exps; fp32-as-u16 => ~60% ----
__global__ void detect_dtype(const u16* __restrict__ xs, int* __restrict__ flag) {
    __shared__ int cnt[256];
    int c = 0;
    for (int i = 0; i < 16; i++) {
        u16 v = xs[threadIdx.x * 16 + i];
        unsigned e = (v >> 7) & 0xFFu;
        c += (e >= 100u && e <= 150u) ? 1 : 0;
    }
    cnt[threadIdx.x] = c;
    __syncthreads();
    for (int s = 128; s > 0; s >>= 1) {
        if (threadIdx.x < s) cnt[threadIdx.x] += cnt[threadIdx.x + s];
        __syncthreads();
    }
    if (threadIdx.x == 0) flag[0] = (cnt[0] >= 3686) ? 1 : 0;   // >=90% sane -> bf16
}

// ---------------- transpose W[K,300] -> T[300,K], output always bf16 ----------------
template<bool BF16>
__global__ void transpose_w(const void* __restrict__ W, u16* __restrict__ T, int K,
                            const int* __restrict__ flag) {
    if ((flag[0] != 0) != BF16) return;
    int idx = blockIdx.x * 256 + threadIdx.x;
    if (idx < 300 * K) {
        int n = idx / K, k = idx % K;
        if (BF16) T[idx] = sb16(((const u16*)W)[k * 300 + n]);
        else      T[idx] = f2b(scrub(((const float*)W)[k * 300 + n]));
    }
}

// ---------------- CSR build (dtype-independent) ----------------
__global__ void count_deg(const int* __restrict__ src, const int* __restrict__ dst, int E,
                          int* __restrict__ outd, int* __restrict__ ind) {
    int e = blockIdx.x * 256 + threadIdx.x;
    if (e < E) {
        atomicAdd(&outd[src[e]], 1);
        atomicAdd(&ind[dst[e]], 1);
    }
}

__global__ void alloc_norm(int Nn,
                           const int* __restrict__ odR, const int* __restrict__ idR,
                           const int* __restrict__ odC, const int* __restrict__ idC,
                           int* __restrict__ offR, int* __restrict__ offC,
                           float* __restrict__ nsR, float* __restrict__ ndR,
                           float* __restrict__ nsC, float* __restrict__ ndC,
                           int* __restrict__ cur2) {
    int i = blockIdx.x * 256 + threadIdx.x;
    if (i >= Nn) return;
    offR[i] = atomicAdd(&cur2[0], idR[i]);
    offC[i] = atomicAdd(&cur2[1], idC[i]);
    nsR[i] = odR[i] > 0 ? rsqrtf((float)odR[i]) : 0.f;
    ndR[i] = idR[i] > 0 ? rsqrtf((float)idR[i]) : 0.f;
    nsC[i] = odC[i] > 0 ? rsqrtf((float)odC[i]) : 0.f;
    ndC[i] = idC[i] > 0 ? rsqrtf((float)idC[i]) : 0.f;
}

__global__ void fill_csr(const int* __restrict__ src, const int* __restrict__ dst, int E,
                         const int* __restrict__ offs, int* __restrict__ cursor,
                         int* __restrict__ adj) {
    int e = blockIdx.x * 256 + threadIdx.x;
    if (e < E) {
        int d = dst[e];
        int p = offs[d] + atomicAdd(&cursor[d], 1);
        adj[p] = src[e];
    }
}

// ---------------- load helpers ----------------
template<bool BF16>
__device__ __forceinline__ float4 ld4(const void* base, size_t row, int off) {
    if (BF16) {
        const u16* p = (const u16*)base + row * DFEAT + off;
        ushort4 v = *(const ushort4*)p;
        return make_float4(b2f(v.x), b2f(v.y), b2f(v.z), b2f(v.w));
    } else {
        const float* p = (const float*)base + row * DFEAT + off;
        return *(const float4*)p;
    }
}
template<bool BF16>
__device__ __forceinline__ float ldp(const void* p, int i) {
    return BF16 ? b2f(((const u16*)p)[i]) : ((const float*)p)[i];
}

// ---------------- megakernel helpers ----------------
template<bool BF16>
__device__ __forceinline__ void agg_tile(
    const void* __restrict__ x, const int* __restrict__ adj, const int* __restrict__ offs,
    const int* __restrict__ deg, const float* __restrict__ ns, const float* __restrict__ nd,
    u16* Xt, int w, int lane, int r0, int Nn) {
    const bool part = lane < 11;           // lanes 0..10 cover cols 256..299
#pragma unroll 1
    for (int i = 0; i < 16; i++) {
        int row = w * 16 + i, node = r0 + row;
        float a0 = 0, a1 = 0, a2 = 0, a3 = 0, p0 = 0, p1 = 0, p2 = 0, p3 = 0;
        if (node < Nn) {
            int bg = offs[node], cnt = deg[node];
#pragma unroll 1
            for (int j = 0; j < cnt; j++) {
                int s = adj[bg + j];
                float nv = ns[s];
                float4 v = ld4<BF16>(x, (size_t)s, 4 * lane);
                a0 += v.x * nv; a1 += v.y * nv; a2 += v.z * nv; a3 += v.w * nv;
                if (part) {
                    float4 u = ld4<BF16>(x, (size_t)s, 256 + 4 * lane);
                    p0 += u.x * nv; p1 += u.y * nv; p2 += u.z * nv; p3 += u.w * nv;
                }
            }
            float ndv = nd[node];
            a0 = scrub(a0 * ndv); a1 = scrub(a1 * ndv);
            a2 = scrub(a2 * ndv); a3 = scrub(a3 * ndv);
            p0 = scrub(p0 * ndv); p1 = scrub(p1 * ndv);
            p2 = scrub(p2 * ndv); p3 = scrub(p3 * ndv);
        }
        u16* orow = Xt + row * XSTR;
        *(ushort4*)(orow + 4 * lane) = make_ushort4(f2b(a0), f2b(a1), f2b(a2), f2b(a3));
        if (part)
            *(ushort4*)(orow + 256 + 4 * lane) = make_ushort4(f2b(p0), f2b(p1), f2b(p2), f2b(p3));
        else if (lane < 14)   // zero pads 300..311 (lanes 11,12,13)
            *(ushort4*)(orow + 300 + 4 * (lane - 11)) = make_ushort4(0, 0, 0, 0);
    }
}

// One K=300 GEMM pass over the wave-private Xt band; accumulates into acc[19]. All-bf16.
__device__ __forceinline__ void gemm300(
    const u16* __restrict__ Bp, int ldb,
    const u16* Xt, u16* Btl, int tid, int arow, int quad, int lm, f32x4* acc) {
    for (int k0 = 0; k0 < 300; k0 += 32) {
        for (int idx = tid; idx < 304 * 8; idx += 256) {
            int n = idx >> 3, kg = idx & 7;
            int kk = k0 + kg * 4;
            ushort4 v = make_ushort4(0, 0, 0, 0);
            if (n < 300 && kk < 300) v = *(const ushort4*)(Bp + (size_t)n * ldb + kk);
            *(ushort4*)(Btl + n * 40 + kg * 4) = v;
        }
        __syncthreads();
        int ka = k0 + quad * 8;
        short8 af = {0, 0, 0, 0, 0, 0, 0, 0};
        if (ka < 300) af = *(const short8*)(Xt + arow * XSTR + ka);   // pads 300..311 zero
#pragma unroll
        for (int t = 0; t < 19; t++) {
            short8 bf = *(const short8*)(Btl + (16 * t + lm) * 40 + quad * 8);
            acc[t] = __builtin_amdgcn_mfma_f32_16x16x32_bf16(af, bf, acc[t], 0, 0, 0);
        }
        __syncthreads();
    }
}

// MODE 0: relu(acc+bias) -> Xt ; MODE 1: LN(acc+bias) -> Xt ; MODE 2: LN(acc+bias) -> global
template<int MODE, bool BF16>
__device__ __forceinline__ void epilogue(
    f32x4* acc, const void* __restrict__ bias, const void* __restrict__ gamma,
    const void* __restrict__ beta, u16* Xt, void* __restrict__ outg,
    int w, int quad, int lm, int r0, int Nn) {
    if (MODE == 0) {
#pragma unroll
        for (int t = 0; t < 19; t++) {
            int col = 16 * t + lm;
            if (col < 300) {
                float bb = ldp<BF16>(bias, col);
#pragma unroll
                for (int r = 0; r < 4; r++) {
                    float v = scrub(acc[t][r] + bb);
                    v = v > 0.f ? v : 0.f;
                    Xt[(w * 16 + quad * 4 + r) * XSTR + col] = f2b(v);
                }
            }
        }
    } else {
        float sum[4] = {0, 0, 0, 0}, ssq[4] = {0, 0, 0, 0};
#pragma unroll
        for (int t = 0; t < 19; t++) {
            int col = 16 * t + lm;
            bool cv = col < 300;
            float bb = cv ? ldp<BF16>(bias, col) : 0.f;
#pragma unroll
            for (int r = 0; r < 4; r++) {
                float v = cv ? scrub(acc[t][r] + bb) : 0.f;
                acc[t][r] = v;
                sum[r] += v;
                ssq[r] += v * v;
            }
        }
#pragma unroll
        for (int off = 1; off < 16; off <<= 1) {
#pragma unroll
            for (int r = 0; r < 4; r++) {
                sum[r] += __shfl_xor(sum[r], off);
                ssq[r] += __shfl_xor(ssq[r], off);
            }
        }
        float mean[4], inv[4];
#pragma unroll
        for (int r = 0; r < 4; r++) {
            mean[r] = sum[r] * (1.f / 300.f);
            float var = fmaxf(ssq[r] * (1.f / 300.f) - mean[r] * mean[r], 0.f);
            inv[r] = rsqrtf(var + 1e-5f);
        }
#pragma unroll
        for (int t = 0; t < 19; t++) {
            int col = 16 * t + lm;
            if (col < 300) {
                float g = ldp<BF16>(gamma, col), be = ldp<BF16>(beta, col);
#pragma unroll
                for (int r = 0; r < 4; r++) {
                    float v = (acc[t][r] - mean[r]) * inv[r] * g + be;
                    if (MODE == 1) {
                        Xt[(w * 16 + quad * 4 + r) * XSTR + col] = f2b(v);
                    } else {
                        int row = r0 + w * 16 + quad * 4 + r;
                        if (row < Nn) {
                            if (BF16) ((u16*)outg)[(size_t)row * 300 + col] = f2b(v);
                            else      ((float*)outg)[(size_t)row * 300 + col] = v;
                        }
                    }
                }
            }
        }
    }
}

// ---------------- fused GNN megakernel: 64 rows per block ----------------
template<bool BF16>
__global__ __launch_bounds__(256) void fused_gnn(
    const void* __restrict__ x,
    const int* __restrict__ adjR, const int* __restrict__ offR, const int* __restrict__ degR,
    const float* __restrict__ nsR, const float* __restrict__ ndR,
    const int* __restrict__ adjC, const int* __restrict__ offC, const int* __restrict__ degC,
    const float* __restrict__ nsC, const float* __restrict__ ndC,
    const u16* __restrict__ WrT, const void* __restrict__ br,
    const u16* __restrict__ WrsT, const void* __restrict__ brs,
    const void* __restrict__ g_rs, const void* __restrict__ b_rs,
    const u16* __restrict__ WcT, const void* __restrict__ bc,
    const u16* __restrict__ WcsT, const void* __restrict__ bcs,
    const void* __restrict__ g_cs, const void* __restrict__ b_cs,
    const u16* __restrict__ WmT, const void* __restrict__ bm,
    const void* __restrict__ g_m, const void* __restrict__ b_m,
    void* __restrict__ out, int Nn, const int* __restrict__ flag) {
    if ((flag[0] != 0) != BF16) return;

    __shared__ __align__(16) u16 Xt[64 * XSTR];     // 39,936 B
    __shared__ __align__(16) u16 Btl[304 * 40];     // 24,320 B

    const int tid = threadIdx.x, w = tid >> 6, lane = tid & 63;
    const int quad = lane >> 4, lm = lane & 15;
    const int r0 = blockIdx.x * 64;
    const int arow = w * 16 + lm;

    f32x4 acc[19], accM[19];

    // ---- row chain ----
    agg_tile<BF16>(x, adjR, offR, degR, nsR, ndR, Xt, w, lane, r0, Nn);
#pragma unroll
    for (int t = 0; t < 19; t++) acc[t] = (f32x4){0.f, 0.f, 0.f, 0.f};
    gemm300(WrT, 300, Xt, Btl, tid, arow, quad, lm, acc);
    epilogue<0, BF16>(acc, br, nullptr, nullptr, Xt, nullptr, w, quad, lm, r0, Nn);

#pragma unroll
    for (int t = 0; t < 19; t++) acc[t] = (f32x4){0.f, 0.f, 0.f, 0.f};
    gemm300(WrsT, 300, Xt, Btl, tid, arow, quad, lm, acc);
    epilogue<1, BF16>(acc, brs, g_rs, b_rs, Xt, nullptr, w, quad, lm, r0, Nn);

#pragma unroll
    for (int t = 0; t < 19; t++) accM[t] = (f32x4){0.f, 0.f, 0.f, 0.f};
    gemm300(WmT, 600, Xt, Btl, tid, arow, quad, lm, accM);        // rowS @ Wm[0:300,:]

    // ---- col chain ----
    agg_tile<BF16>(x, adjC, offC, degC, nsC, ndC, Xt, w, lane, r0, Nn);
#pragma unroll
    for (int t = 0; t < 19; t++) acc[t] = (f32x4){0.f, 0.f, 0.f, 0.f};
    gemm300(WcT, 300, Xt, Btl, tid, arow, quad, lm, acc);
    epilogue<0, BF16>(acc, bc, nullptr, nullptr, Xt, nullptr, w, quad, lm, r0, Nn);

#pragma unroll
    for (int t = 0; t < 19; t++) acc[t] = (f32x4){0.f, 0.f, 0.f, 0.f};
    gemm300(WcsT, 300, Xt, Btl, tid, arow, quad, lm, acc);
    epilogue<1, BF16>(acc, bcs, g_cs, b_cs, Xt, nullptr, w, quad, lm, r0, Nn);

    gemm300(WmT + 300, 600, Xt, Btl, tid, arow, quad, lm, accM);  // += colS @ Wm[300:600,:]

    epilogue<2, BF16>(accM, bm, g_m, b_m, Xt, out, w, quad, lm, r0, Nn);
}

extern "C" void kernel_launch(void* const* d_in, const int* in_sizes, int n_in,
                              void* d_out, int out_size, void* d_ws, size_t ws_size,
                              hipStream_t stream) {
    (void)n_in; (void)out_size; (void)ws_size;
    const void* x   = d_in[0];
    const int* re   = (const int*)d_in[1];
    const int* ce   = (const int*)d_in[2];

    const int Nn = in_sizes[0] / DFEAT;
    const int Er = in_sizes[1] / 2;
    const int Ec = in_sizes[2] / 2;

    char* p = (char*)d_ws;
    size_t off = 0;
    auto balloc = [&](size_t bytes) -> void* {
        void* r = p + off;
        off += (bytes + 255) & ~(size_t)255;
        return r;
    };
    // --- zeroed region first ---
    int* degR  = (int*)balloc((size_t)Nn * 4);   // in-degree (row graph)
    int* odegR = (int*)balloc((size_t)Nn * 4);   // out-degree
    int* degC  = (int*)balloc((size_t)Nn * 4);
    int* odegC = (int*)balloc((size_t)Nn * 4);
    int* curR  = (int*)balloc((size_t)Nn * 4);
    int* curC  = (int*)balloc((size_t)Nn * 4);
    int* cur2  = (int*)balloc(64 * 4);
    size_t zbytes = off;
    // --- rest ---
    int* flag  = (int*)balloc(256);
    int* offsR = (int*)balloc((size_t)Nn * 4);
    int* offsC = (int*)balloc((size_t)Nn * 4);
    float* nsR = (float*)balloc((size_t)Nn * 4);
    float* ndR = (float*)balloc((size_t)Nn * 4);
    float* nsC = (float*)balloc((size_t)Nn * 4);
    float* ndC = (float*)balloc((size_t)Nn * 4);
    int* adjR  = (int*)balloc((size_t)Er * 4);
    int* adjC  = (int*)balloc((size_t)Ec * 4);
    u16* WrT   = (u16*)balloc(300 * 300 * 2);
    u16* WcT   = (u16*)balloc(300 * 300 * 2);
    u16* WrsT  = (u16*)balloc(300 * 300 * 2);
    u16* WcsT  = (u16*)balloc(300 * 300 * 2);
    u16* WmT   = (u16*)balloc(300 * 600 * 2);
    // total ws usage ~14.3 MB

    detect_dtype<<<1, 256, 0, stream>>>((const u16*)x, flag);
    hipMemsetAsync(d_ws, 0, zbytes, stream);

#define TP(Wsrc, Tdst, K)                                                            \
    transpose_w<true><<<((300 * (K)) + 255) / 256, 256, 0, stream>>>(Wsrc, Tdst, K, flag); \
    transpose_w<false><<<((300 * (K)) + 255) / 256, 256, 0, stream>>>(Wsrc, Tdst, K, flag)
    TP(d_in[3], WrT, 300);
    TP(d_in[5], WcT, 300);
    TP(d_in[7], WrsT, 300);
    TP(d_in[11], WcsT, 300);
    TP(d_in[15], WmT, 600);
#undef TP

    count_deg<<<(Er + 255) / 256, 256, 0, stream>>>(re, re + Er, Er, odegR, degR);
    count_deg<<<(Ec + 255) / 256, 256, 0, stream>>>(ce, ce + Ec, Ec, odegC, degC);
    alloc_norm<<<(Nn + 255) / 256, 256, 0, stream>>>(Nn, odegR, degR, odegC, degC,
                                                     offsR, offsC, nsR, ndR, nsC, ndC, cur2);
    fill_csr<<<(Er + 255) / 256, 256, 0, stream>>>(re, re + Er, Er, offsR, curR, adjR);
    fill_csr<<<(Ec + 255) / 256, 256, 0, stream>>>(ce, ce + Ec, Ec, offsC, curC, adjC);

    const int gb = (Nn + 63) / 64;
    fused_gnn<true><<<gb, 256, 0, stream>>>(
        x, adjR, offsR, degR, nsR, ndR, adjC, offsC, degC, nsC, ndC,
        WrT, d_in[4], WrsT, d_in[8], d_in[9], d_in[10],
        WcT, d_in[6], WcsT, d_in[12], d_in[13], d_in[14],
        WmT, d_in[16], d_in[17], d_in[18], d_out, Nn, flag);
    fused_gnn<false><<<gb, 256, 0, stream>>>(
        x, adjR, offsR, degR, nsR, ndR, adjC, offsC, degC, nsC, ndC,
        WrT, d_in[4], WrsT, d_in[8], d_in[9], d_in[10],
        WcT, d_in[6], WcsT, d_in[12], d_in[13], d_in[14],
        WmT, d_in[16], d_in[17], d_in[18], d_out, Nn, flag);
}

// Round 4
// 1793.025 us; speedup vs baseline: 2.0953x; 2.0953x over previous
//
#include <hip/hip_runtime.h>
#include <stdint.h>

#define DFEAT 300

typedef unsigned short u16;
using short8 = __attribute__((ext_vector_type(8))) short;
using f32x4  = __attribute__((ext_vector_type(4))) float;

__device__ __forceinline__ float b2f(u16 u) {
    return __uint_as_float(((unsigned)u) << 16);
}
__device__ __forceinline__ u16 f2b(float f) {
    unsigned u = __float_as_uint(f);
    return (u16)((u + 0x7FFFu + ((u >> 16) & 1u)) >> 16);   // RNE
}
__device__ __forceinline__ float scrub(float v) {           // kill NaN/Inf
    unsigned u = __float_as_uint(v);
    return (((u >> 23) & 0xFFu) == 0xFFu) ? 0.f : v;
}
__device__ __forceinline__ u16 sb16(u16 v) {
    return (((v >> 7) & 0xFFu) == 0xFFu) ? (u16)0 : v;
}

// ---------------- dtype sniffer: bf16 N(0,1) => ~100% sane exps; fp32-as-u16 => ~60% ----
__global__ void detect_dtype(const u16* __restrict__ xs, int* __restrict__ flag) {
    __shared__ int cnt[256];
    int c = 0;
    for (int i = 0; i < 16; i++) {
        u16 v = xs[threadIdx.x * 16 + i];
        unsigned e = (v >> 7) & 0xFFu;
        c += (e >= 100u && e <= 150u) ? 1 : 0;
    }
    cnt[threadIdx.x] = c;
    __syncthreads();
    for (int s = 128; s > 0; s >>= 1) {
        if (threadIdx.x < s) cnt[threadIdx.x] += cnt[threadIdx.x + s];
        __syncthreads();
    }
    if (threadIdx.x == 0) flag[0] = (cnt[0] >= 3686) ? 1 : 0;   // >=90% sane -> bf16
}

// ---------------- x -> bf16 canonical table ----------------
template<bool BF16>
__global__ __launch_bounds__(256) void conv_x(const void* __restrict__ x, u16* __restrict__ xb,
                                              long total8, const int* __restrict__ flag) {
    if ((flag[0] != 0) != BF16) return;
    long idx = (long)blockIdx.x * 256 + threadIdx.x;
    if (idx >= total8) return;
    long base = idx * 8;
    if (BF16) {
        const u16* p = (const u16*)x + base;
        ushort4 a = *(const ushort4*)p, b = *(const ushort4*)(p + 4);
        *(ushort4*)(xb + base) = a;
        *(ushort4*)(xb + base + 4) = b;
    } else {
        const float* p = (const float*)x + base;
        float4 a = *(const float4*)p, b = *(const float4*)(p + 4);
        *(ushort4*)(xb + base) = make_ushort4(f2b(scrub(a.x)), f2b(scrub(a.y)), f2b(scrub(a.z)), f2b(scrub(a.w)));
        *(ushort4*)(xb + base + 4) = make_ushort4(f2b(scrub(b.x)), f2b(scrub(b.y)), f2b(scrub(b.z)), f2b(scrub(b.w)));
    }
}

// ---------------- transpose W[K,300] -> T[300,K], output bf16 ----------------
template<bool BF16>
__global__ void transpose_w(const void* __restrict__ W, u16* __restrict__ T, int K,
                            const int* __restrict__ flag) {
    if ((flag[0] != 0) != BF16) return;
    int idx = blockIdx.x * 256 + threadIdx.x;
    if (idx < 300 * K) {
        int n = idx / K, k = idx % K;
        if (BF16) T[idx] = sb16(((const u16*)W)[k * 300 + n]);
        else      T[idx] = f2b(scrub(((const float*)W)[k * 300 + n]));
    }
}

// ---------------- params -> fp32 pbuf[11][304] ----------------
template<bool BF16>
__global__ void conv_params(const void* p0, const void* p1, const void* p2, const void* p3,
                            const void* p4, const void* p5, const void* p6, const void* p7,
                            const void* p8, const void* p9, const void* p10,
                            float* __restrict__ pbuf, const int* __restrict__ flag) {
    if ((flag[0] != 0) != BF16) return;
    int idx = blockIdx.x * 256 + threadIdx.x;
    if (idx >= 11 * 304) return;
    int j = idx / 304, c = idx % 304;
    const void* ps[11] = {p0, p1, p2, p3, p4, p5, p6, p7, p8, p9, p10};
    float v = 0.f;
    if (c < 300) {
        if (BF16) v = b2f(sb16(((const u16*)ps[j])[c]));
        else      v = scrub(((const float*)ps[j])[c]);
    }
    pbuf[j * 304 + c] = v;
}

// ---------------- CSR build ----------------
__global__ void count_deg(const int* __restrict__ src, const int* __restrict__ dst, int E,
                          int* __restrict__ outd, int* __restrict__ ind) {
    int e = blockIdx.x * 256 + threadIdx.x;
    if (e < E) {
        atomicAdd(&outd[src[e]], 1);
        atomicAdd(&ind[dst[e]], 1);
    }
}

// block-scan offset allocation: ONE global atomic per block per graph
__global__ __launch_bounds__(256) void alloc_norm(int Nn,
                           const int* __restrict__ odR, const int* __restrict__ idR,
                           const int* __restrict__ odC, const int* __restrict__ idC,
                           int* __restrict__ offR, int* __restrict__ offC,
                           float* __restrict__ nsR, float* __restrict__ ndR,
                           float* __restrict__ nsC, float* __restrict__ ndC,
                           int* __restrict__ cur2) {
    __shared__ int sR[256], sC[256];
    __shared__ int baseR, baseC;
    int tid = threadIdx.x;
    int i = blockIdx.x * 256 + tid;
    int dR = (i < Nn) ? idR[i] : 0;
    int dC = (i < Nn) ? idC[i] : 0;
    sR[tid] = dR; sC[tid] = dC;
    __syncthreads();
    for (int off = 1; off < 256; off <<= 1) {          // Hillis-Steele inclusive scan
        int vR = (tid >= off) ? sR[tid - off] : 0;
        int vC = (tid >= off) ? sC[tid - off] : 0;
        __syncthreads();
        sR[tid] += vR; sC[tid] += vC;
        __syncthreads();
    }
    if (tid == 0) {
        baseR = atomicAdd(&cur2[0], sR[255]);
        baseC = atomicAdd(&cur2[1], sC[255]);
    }
    __syncthreads();
    if (i < Nn) {
        offR[i] = baseR + sR[tid] - dR;
        offC[i] = baseC + sC[tid] - dC;
        nsR[i] = odR[i] > 0 ? rsqrtf((float)odR[i]) : 0.f;
        ndR[i] = idR[i] > 0 ? rsqrtf((float)idR[i]) : 0.f;
        nsC[i] = odC[i] > 0 ? rsqrtf((float)odC[i]) : 0.f;
        ndC[i] = idC[i] > 0 ? rsqrtf((float)idC[i]) : 0.f;
    }
}

__global__ void fill_csr(const int* __restrict__ src, const int* __restrict__ dst, int E,
                         const int* __restrict__ offs, int* __restrict__ cursor,
                         int* __restrict__ adj) {
    int e = blockIdx.x * 256 + threadIdx.x;
    if (e < E) {
        int d = dst[e];
        int p = offs[d] + atomicAdd(&cursor[d], 1);
        adj[p] = src[e];
    }
}

// ---------------- aggregation: one wave per node, full occupancy, unroll-2 ILP ----------------
__global__ __launch_bounds__(256) void aggregate(
    const u16* __restrict__ xb, const int* __restrict__ adj, const int* __restrict__ offs,
    const int* __restrict__ deg, const float* __restrict__ ns, const float* __restrict__ nd,
    u16* __restrict__ agg, int Nn) {
    int w = threadIdx.x >> 6, lane = threadIdx.x & 63;
    int node = blockIdx.x * 4 + w;
    if (node >= Nn) return;
    int bg = offs[node], cnt = deg[node];
    const bool part = lane < 11;                 // lanes 0..10 -> cols 256..299
    const int c0 = 4 * lane, c1 = 256 + 4 * lane;
    float a0 = 0, a1 = 0, a2 = 0, a3 = 0, p0 = 0, p1 = 0, p2 = 0, p3 = 0;
    int j = 0;
    for (; j + 2 <= cnt; j += 2) {
        int s0 = adj[bg + j], s1 = adj[bg + j + 1];
        float n0 = ns[s0], n1 = ns[s1];
        const u16* r0p = xb + (size_t)s0 * DFEAT;
        const u16* r1p = xb + (size_t)s1 * DFEAT;
        ushort4 v0 = *(const ushort4*)(r0p + c0);
        ushort4 v1 = *(const ushort4*)(r1p + c0);
        a0 += b2f(v0.x) * n0 + b2f(v1.x) * n1;
        a1 += b2f(v0.y) * n0 + b2f(v1.y) * n1;
        a2 += b2f(v0.z) * n0 + b2f(v1.z) * n1;
        a3 += b2f(v0.w) * n0 + b2f(v1.w) * n1;
        if (part) {
            ushort4 u0 = *(const ushort4*)(r0p + c1);
            ushort4 u1 = *(const ushort4*)(r1p + c1);
            p0 += b2f(u0.x) * n0 + b2f(u1.x) * n1;
            p1 += b2f(u0.y) * n0 + b2f(u1.y) * n1;
            p2 += b2f(u0.z) * n0 + b2f(u1.z) * n1;
            p3 += b2f(u0.w) * n0 + b2f(u1.w) * n1;
        }
    }
    if (j < cnt) {
        int s = adj[bg + j];
        float nv = ns[s];
        const u16* rp = xb + (size_t)s * DFEAT;
        ushort4 v = *(const ushort4*)(rp + c0);
        a0 += b2f(v.x) * nv; a1 += b2f(v.y) * nv; a2 += b2f(v.z) * nv; a3 += b2f(v.w) * nv;
        if (part) {
            ushort4 u = *(const ushort4*)(rp + c1);
            p0 += b2f(u.x) * nv; p1 += b2f(u.y) * nv; p2 += b2f(u.z) * nv; p3 += b2f(u.w) * nv;
        }
    }
    float ndv = nd[node];
    u16* o = agg + (size_t)node * DFEAT;
    *(ushort4*)(o + c0) = make_ushort4(f2b(a0 * ndv), f2b(a1 * ndv), f2b(a2 * ndv), f2b(a3 * ndv));
    if (part)
        *(ushort4*)(o + c1) = make_ushort4(f2b(p0 * ndv), f2b(p1 * ndv), f2b(p2 * ndv), f2b(p3 * ndv));
}

// ---------------- GEMM + fused epilogue ----------------
// C[M,300] over A[M,Ktot] (= A1[:, :K1] ++ A2[:, K1:]) x Bt[300,Ktot].
// MODE 0: relu -> bf16 out. MODE 1: LN -> bf16 out. MODE 2: LN -> d_out (bf16/f32 by OUTF32).
template<int MODE, bool OUTF32>
__global__ __launch_bounds__(256) void gemm_k(
    const u16* __restrict__ A1, const u16* __restrict__ A2, int K1, int Ktot,
    const u16* __restrict__ Bt, const float* __restrict__ bias,
    const float* __restrict__ gamma, const float* __restrict__ beta,
    void* __restrict__ out, int M, const int* __restrict__ flag) {
    if (MODE == 2) {
        // inputs bf16 (flag=1) -> bf16 out (OUTF32=false); fp32 inputs -> fp32 out
        if ((flag[0] != 0) != (!OUTF32)) return;
    }
    __shared__ __align__(16) u16 Btl[304 * 40];   // [n][k] tile, stride 40

    const int tid = threadIdx.x, w = tid >> 6, lane = tid & 63;
    const int quad = lane >> 4, lm = lane & 15;
    const int r0 = blockIdx.x * 64;
    const int rowA = min(r0 + w * 16 + lm, M - 1);
    const int K2 = Ktot - K1;
    const u16* rp1 = A1 + (size_t)rowA * K1;
    const u16* rp2 = A2 + (size_t)rowA * (K2 > 0 ? K2 : 1);

    f32x4 acc[19];
#pragma unroll
    for (int t = 0; t < 19; t++) acc[t] = (f32x4){0.f, 0.f, 0.f, 0.f};

    for (int k0 = 0; k0 < Ktot; k0 += 32) {
        for (int idx = tid; idx < 304 * 8; idx += 256) {
            int n = idx >> 3, kg = idx & 7;
            int kk = k0 + kg * 4;
            ushort4 v = make_ushort4(0, 0, 0, 0);
            if (n < 300 && kk < Ktot) v = *(const ushort4*)(Bt + (size_t)n * Ktot + kk);
            *(ushort4*)(Btl + n * 40 + kg * 4) = v;
        }
        __syncthreads();
        int ka = k0 + quad * 8;
        ushort4 a0 = make_ushort4(0, 0, 0, 0), a1 = make_ushort4(0, 0, 0, 0);
        if (ka < Ktot)
            a0 = (ka < K1) ? *(const ushort4*)(rp1 + ka) : *(const ushort4*)(rp2 + ka - K1);
        if (ka + 4 < Ktot)
            a1 = (ka + 4 < K1) ? *(const ushort4*)(rp1 + ka + 4) : *(const ushort4*)(rp2 + ka + 4 - K1);
        short8 af;
        af[0] = (short)a0.x; af[1] = (short)a0.y; af[2] = (short)a0.z; af[3] = (short)a0.w;
        af[4] = (short)a1.x; af[5] = (short)a1.y; af[6] = (short)a1.z; af[7] = (short)a1.w;
#pragma unroll
        for (int t = 0; t < 19; t++) {
            short8 bf = *(const short8*)(Btl + (16 * t + lm) * 40 + quad * 8);
            acc[t] = __builtin_amdgcn_mfma_f32_16x16x32_bf16(af, bf, acc[t], 0, 0, 0);
        }
        __syncthreads();
    }

    const int rowbase = r0 + w * 16 + quad * 4;
    if (MODE == 0) {
#pragma unroll
        for (int t = 0; t < 19; t++) {
            int col = 16 * t + lm;
            if (col < 300) {
                float bb = bias[col];
#pragma unroll
                for (int r = 0; r < 4; r++) {
                    int row = rowbase + r;
                    if (row < M) {
                        float v = scrub(acc[t][r] + bb);
                        v = v > 0.f ? v : 0.f;
                        ((u16*)out)[(size_t)row * 300 + col] = f2b(v);
                    }
                }
            }
        }
    } else {
        float sum[4] = {0, 0, 0, 0}, ssq[4] = {0, 0, 0, 0};
#pragma unroll
        for (int t = 0; t < 19; t++) {
            int col = 16 * t + lm;
            bool cv = col < 300;
            float bb = cv ? bias[col] : 0.f;
#pragma unroll
            for (int r = 0; r < 4; r++) {
                float v = cv ? scrub(acc[t][r] + bb) : 0.f;
                acc[t][r] = v;
                sum[r] += v;
                ssq[r] += v * v;
            }
        }
#pragma unroll
        for (int off = 1; off < 16; off <<= 1) {
#pragma unroll
            for (int r = 0; r < 4; r++) {
                sum[r] += __shfl_xor(sum[r], off);
                ssq[r] += __shfl_xor(ssq[r], off);
            }
        }
        float mean[4], inv[4];
#pragma unroll
        for (int r = 0; r < 4; r++) {
            mean[r] = sum[r] * (1.f / 300.f);
            float var = fmaxf(ssq[r] * (1.f / 300.f) - mean[r] * mean[r], 0.f);
            inv[r] = rsqrtf(var + 1e-5f);
        }
#pragma unroll
        for (int t = 0; t < 19; t++) {
            int col = 16 * t + lm;
            if (col < 300) {
                float g = gamma[col], be = beta[col];
#pragma unroll
                for (int r = 0; r < 4; r++) {
                    int row = rowbase + r;
                    if (row < M) {
                        float v = (acc[t][r] - mean[r]) * inv[r] * g + be;
                        if (MODE == 1)      ((u16*)out)[(size_t)row * 300 + col] = f2b(v);
                        else if (OUTF32)    ((float*)out)[(size_t)row * 300 + col] = v;
                        else                ((u16*)out)[(size_t)row * 300 + col] = f2b(v);
                    }
                }
            }
        }
    }
}

extern "C" void kernel_launch(void* const* d_in, const int* in_sizes, int n_in,
                              void* d_out, int out_size, void* d_ws, size_t ws_size,
                              hipStream_t stream) {
    (void)n_in; (void)out_size; (void)ws_size;
    const void* x   = d_in[0];
    const int* re   = (const int*)d_in[1];
    const int* ce   = (const int*)d_in[2];

    const int Nn = in_sizes[0] / DFEAT;
    const int Er = in_sizes[1] / 2;
    const int Ec = in_sizes[2] / 2;

    char* p = (char*)d_ws;
    size_t off = 0;
    auto balloc = [&](size_t bytes) -> void* {
        void* r = p + off;
        off += (bytes + 255) & ~(size_t)255;
        return r;
    };
    // --- zeroed region first ---
    int* degR  = (int*)balloc((size_t)Nn * 4);   // in-degree (row)
    int* odegR = (int*)balloc((size_t)Nn * 4);
    int* degC  = (int*)balloc((size_t)Nn * 4);
    int* odegC = (int*)balloc((size_t)Nn * 4);
    int* curR  = (int*)balloc((size_t)Nn * 4);
    int* curC  = (int*)balloc((size_t)Nn * 4);
    int* cur2  = (int*)balloc(64 * 4);
    size_t zbytes = off;
    // --- rest ---
    int* flag  = (int*)balloc(256);
    int* offsR = (int*)balloc((size_t)Nn * 4);
    int* offsC = (int*)balloc((size_t)Nn * 4);
    float* nsR = (float*)balloc((size_t)Nn * 4);
    float* ndR = (float*)balloc((size_t)Nn * 4);
    float* nsC = (float*)balloc((size_t)Nn * 4);
    float* ndC = (float*)balloc((size_t)Nn * 4);
    int* adjR  = (int*)balloc((size_t)Er * 4);
    int* adjC  = (int*)balloc((size_t)Ec * 4);
    u16* WrT   = (u16*)balloc(300 * 300 * 2);
    u16* WcT   = (u16*)balloc(300 * 300 * 2);
    u16* WrsT  = (u16*)balloc(300 * 300 * 2);
    u16* WcsT  = (u16*)balloc(300 * 300 * 2);
    u16* WmT   = (u16*)balloc(300 * 600 * 2);
    float* pbuf = (float*)balloc(11 * 304 * 4);
    u16* xb    = (u16*)balloc((size_t)Nn * DFEAT * 2);   // canonical bf16 features
    u16* B2    = (u16*)balloc((size_t)Nn * DFEAT * 2);   // aggR -> rowg -> rowgS (in-place)
    u16* B3    = (u16*)balloc((size_t)Nn * DFEAT * 2);   // aggC -> colg -> colgS (in-place)
    // total ~194 MB

    const float* pbr  = pbuf + 0 * 304;
    const float* pbc  = pbuf + 1 * 304;
    const float* pbrs = pbuf + 2 * 304;
    const float* pgrs = pbuf + 3 * 304;
    const float* pBrs = pbuf + 4 * 304;
    const float* pbcs = pbuf + 5 * 304;
    const float* pgcs = pbuf + 6 * 304;
    const float* pBcs = pbuf + 7 * 304;
    const float* pbm  = pbuf + 8 * 304;
    const float* pgm  = pbuf + 9 * 304;
    const float* pBm  = pbuf + 10 * 304;

    detect_dtype<<<1, 256, 0, stream>>>((const u16*)x, flag);
    hipMemsetAsync(d_ws, 0, zbytes, stream);

    const long total8 = (long)Nn * DFEAT / 8;
    conv_x<true><<<(int)((total8 + 255) / 256), 256, 0, stream>>>(x, xb, total8, flag);
    conv_x<false><<<(int)((total8 + 255) / 256), 256, 0, stream>>>(x, xb, total8, flag);

#define TP(Wsrc, Tdst, K)                                                                   \
    transpose_w<true><<<((300 * (K)) + 255) / 256, 256, 0, stream>>>(Wsrc, Tdst, K, flag);  \
    transpose_w<false><<<((300 * (K)) + 255) / 256, 256, 0, stream>>>(Wsrc, Tdst, K, flag)
    TP(d_in[3], WrT, 300);
    TP(d_in[5], WcT, 300);
    TP(d_in[7], WrsT, 300);
    TP(d_in[11], WcsT, 300);
    TP(d_in[15], WmT, 600);
#undef TP

    conv_params<true><<<14, 256, 0, stream>>>(d_in[4], d_in[6], d_in[8], d_in[9], d_in[10],
                                              d_in[12], d_in[13], d_in[14], d_in[16], d_in[17],
                                              d_in[18], pbuf, flag);
    conv_params<false><<<14, 256, 0, stream>>>(d_in[4], d_in[6], d_in[8], d_in[9], d_in[10],
                                               d_in[12], d_in[13], d_in[14], d_in[16], d_in[17],
                                               d_in[18], pbuf, flag);

    count_deg<<<(Er + 255) / 256, 256, 0, stream>>>(re, re + Er, Er, odegR, degR);
    count_deg<<<(Ec + 255) / 256, 256, 0, stream>>>(ce, ce + Ec, Ec, odegC, degC);
    alloc_norm<<<(Nn + 255) / 256, 256, 0, stream>>>(Nn, odegR, degR, odegC, degC,
                                                     offsR, offsC, nsR, ndR, nsC, ndC, cur2);
    fill_csr<<<(Er + 255) / 256, 256, 0, stream>>>(re, re + Er, Er, offsR, curR, adjR);
    fill_csr<<<(Ec + 255) / 256, 256, 0, stream>>>(ce, ce + Ec, Ec, offsC, curC, adjC);

    aggregate<<<(Nn + 3) / 4, 256, 0, stream>>>(xb, adjR, offsR, degR, nsR, ndR, B2, Nn);
    aggregate<<<(Nn + 3) / 4, 256, 0, stream>>>(xb, adjC, offsC, degC, nsC, ndC, B3, Nn);

    const int gb = (Nn + 63) / 64;
    // GraphConv linear+relu (in-place on row bands: each block reads only rows it writes)
    gemm_k<0, false><<<gb, 256, 0, stream>>>(B2, B2, 300, 300, WrT, pbr, nullptr, nullptr, B2, Nn, flag);
    gemm_k<0, false><<<gb, 256, 0, stream>>>(B3, B3, 300, 300, WcT, pbc, nullptr, nullptr, B3, Nn, flag);
    // support linear + LN (in-place)
    gemm_k<1, false><<<gb, 256, 0, stream>>>(B2, B2, 300, 300, WrsT, pbrs, pgrs, pBrs, B2, Nn, flag);
    gemm_k<1, false><<<gb, 256, 0, stream>>>(B3, B3, 300, 300, WcsT, pbcs, pgcs, pBcs, B3, Nn, flag);
    // merge GEMM K=600 + LN -> d_out (dtype-matched store, flag-predicated)
    gemm_k<2, false><<<gb, 256, 0, stream>>>(B2, B3, 300, 600, WmT, pbm, pgm, pBm, d_out, Nn, flag);
    gemm_k<2, true ><<<gb, 256, 0, stream>>>(B2, B3, 300, 600, WmT, pbm, pgm, pBm, d_out, Nn, flag);
}